// Round 9
// baseline (652.244 us; speedup 1.0000x reference)
//
#include <hip/hip_runtime.h>

typedef float f32x4 __attribute__((ext_vector_type(4)));
typedef short bf16x8 __attribute__((ext_vector_type(8)));
typedef unsigned short u16;

#define B_SZ 4
#define S_SZ 4096
#define H_SZ 1024
#define F_SZ 4096
#define CHUNK_SZ 512
#define NCHUNK 8
#define MCH 2048            // rows per chunk (B*CHUNK)
#define LRATE 0.001f
#define NSPLIT 4            // split-K factor for GEMM2

__device__ __forceinline__ u16 f2bf(float f) {
  unsigned u = __float_as_uint(f);
  u += 0x7FFFu + ((u >> 16) & 1u);   // round-to-nearest-even
  return (u16)(u >> 16);
}
__device__ __forceinline__ float bf2f(u16 u) {
  return __uint_as_float(((unsigned)u) << 16);
}

__device__ __forceinline__ void gload_lds16(const void* g, void* l) {
  __builtin_amdgcn_global_load_lds(
      (const __attribute__((address_space(1))) unsigned int*)g,
      (__attribute__((address_space(3))) unsigned int*)l, 16, 0, 0);
}

#define VMCNT(n) asm volatile("s_waitcnt vmcnt(" #n ")" ::: "memory")
#define SBAR() __builtin_amdgcn_s_barrier()
#define SCHED_FENCE() __builtin_amdgcn_sched_barrier(0)
#define PRIO1() __builtin_amdgcn_s_setprio(1)
#define PRIO0() __builtin_amdgcn_s_setprio(0)

// ---------------- converts ----------------

__global__ __launch_bounds__(256) void k_init(float* scal) {
  if (threadIdx.x == 0) { scal[0] = 1.f; scal[1] = 0.f; }
}

__global__ __launch_bounds__(256) void k_cvt_x(const float* __restrict__ x,
                                               u16* __restrict__ xb) {
  size_t i = ((size_t)blockIdx.x * 256 + threadIdx.x) * 8;
  float4 v0 = *(const float4*)(x + i);
  float4 v1 = *(const float4*)(x + i + 4);
  union { u16 u[8]; bf16x8 v; } o;
  o.u[0] = f2bf(v0.x); o.u[1] = f2bf(v0.y); o.u[2] = f2bf(v0.z); o.u[3] = f2bf(v0.w);
  o.u[4] = f2bf(v1.x); o.u[5] = f2bf(v1.y); o.u[6] = f2bf(v1.z); o.u[7] = f2bf(v1.w);
  *(bf16x8*)(xb + i) = o.v;
}

// W [R][C] fp32 -> Wt[row = c*rstride + roff][r] bf16  (rstride=2 interleaves w0/w2)
__global__ __launch_bounds__(256) void k_transpose_cvt(const float* __restrict__ W,
                                                       u16* __restrict__ Wt,
                                                       int R, int C, int rstride, int roff) {
  __shared__ float tile[32][33];
  int tx = threadIdx.x & 31, ty = threadIdx.x >> 5;
  int r0 = blockIdx.y << 5, c0 = blockIdx.x << 5;
#pragma unroll
  for (int i = 0; i < 4; i++)
    tile[ty + i * 8][tx] = W[(size_t)(r0 + ty + i * 8) * C + c0 + tx];
  __syncthreads();
#pragma unroll
  for (int i = 0; i < 4; i++)
    Wt[((size_t)(c0 + ty + i * 8) * rstride + roff) * R + r0 + tx] = f2bf(tile[tx][ty + i * 8]);
}

// ---------------- GEMM 1 (true 8-phase, kslice-major LDS): C = Xc @ wgu^T -> SwiGLU -> h ----
// BM=BN=256, BK=64, 512 thr (8 waves 2Mx4N), per-wave C 128x64 (acc[8][4]).
// LDS per operand: [2 buf][2 kslice][256 rows][64B] = 64KB; total 128KB.
// Half-tile = kslice block (16KB = 2 linear 8KB sweeps => 2 gloads/thread).
// Per K-tile: 4 phases {ds_read (8 or 4) | stage 1 half | SBAR | 16 MFMA | SBAR},
// counted vmcnt(4) ONLY at phases 2 and 4 (protects next 2 phases' ds_reads).
__global__ __launch_bounds__(512, 2) void k_gemm_gu8(
    const u16* __restrict__ xb,   // [B][S][H] bf16
    const u16* __restrict__ wgu,  // [8192][1024] bf16 interleaved (2f=w0^T, 2f+1=w2^T)
    u16* __restrict__ hbuf,       // [2048][F] bf16
    const float* __restrict__ scal, int chunk) {
  __shared__ __align__(16) u16 sA[32768];   // 64KB: 2buf x 2ks x 256 x 32 u16
  __shared__ __align__(16) u16 sB[32768];   // 64KB

  int t = threadIdx.x;
  int lane = t & 63, wid = t >> 6;
  int wm = wid >> 2, wn = wid & 3;

  // XCD-bijective: 256 wgs -> 32 contiguous per XCD (4 tn x 8 tm)
  int orig = blockIdx.x;
  int wg = (orig & 7) * 32 + (orig >> 3);
  int tn = wg >> 3, tm = wg & 7;   // tn 0..31, tm 0..7

  int gm0 = tm << 8;
  int bb = gm0 >> 9;
  int pos0 = gm0 & 511;
  const u16* Abase = xb + ((size_t)bb * S_SZ + (size_t)chunk * CHUNK_SZ + pos0) * H_SZ;

  // staging: thread t -> row t>>2 (+128/sweep), 16B-slot t&3 of the 64B row.
  // pre-swizzled source col: slot ^ ((row>>1)&3); sweep-invariant.
  int scol = (((t & 3) ^ ((t >> 3) & 3)) << 3);   // elements within kslice
  const u16* aS = Abase + (size_t)(t >> 2) * H_SZ + scol;
  const u16* bS = wgu + ((size_t)(tn << 8) + (t >> 2)) * H_SZ + scol;

  f32x4 acc[8][4];
#pragma unroll
  for (int i = 0; i < 8; i++)
#pragma unroll
    for (int j = 0; j < 4; j++)
#pragma unroll
      for (int k = 0; k < 4; k++) acc[i][j][k] = 0.f;

  // read side: row = base16 + (lane&15); slot = (lane>>4) ^ ((row>>1)&3) (per-lane const)
  const int rslB = (((lane >> 4)) ^ (((lane & 15) >> 1) & 3)) * 16;
  const int aRowB = ((wm << 7) + (lane & 15)) * 64 + rslB;   // + fr*1024 + ks*16384 + buf*32768
  const int bRowB = ((wn << 6) + (lane & 15)) * 64 + rslB;   // + fc*1024 + ...

#define STA(b_, kt_, ks_) {                                                  \
    const u16* s_ = aS + (size_t)(kt_) * 64 + (ks_) * 32;                    \
    char* d_ = (char*)sA + (b_) * 32768 + (ks_) * 16384 + t * 16;            \
    gload_lds16(s_, d_);                                                     \
    gload_lds16(s_ + (size_t)128 * H_SZ, d_ + 8192); }
#define STB(b_, kt_, ks_) {                                                  \
    const u16* s_ = bS + (size_t)(kt_) * 64 + (ks_) * 32;                    \
    char* d_ = (char*)sB + (b_) * 32768 + (ks_) * 16384 + t * 16;            \
    gload_lds16(s_, d_);                                                     \
    gload_lds16(s_ + (size_t)128 * H_SZ, d_ + 8192); }

#define LDA4(b_, ks_, FRS_) { _Pragma("unroll")                              \
    for (int i_ = 0; i_ < 4; i_++)                                           \
      av[i_] = *(const bf16x8*)((const char*)sA + (b_) * 32768 +             \
                                (ks_) * 16384 + aRowB + (FRS_ + i_) * 1024); }
#define LDB4(b_, ks_) { _Pragma("unroll")                                    \
    for (int j_ = 0; j_ < 4; j_++)                                           \
      bv[j_] = *(const bf16x8*)((const char*)sB + (b_) * 32768 +             \
                                (ks_) * 16384 + bRowB + j_ * 1024); }

#define MFMA16(FRS_) { _Pragma("unroll")                                     \
    for (int i_ = 0; i_ < 4; i_++)                                           \
      _Pragma("unroll")                                                      \
      for (int j_ = 0; j_ < 4; j_++)                                         \
        acc[FRS_ + i_][j_] = __builtin_amdgcn_mfma_f32_16x16x32_bf16(        \
            av[i_], bv[j_], acc[FRS_ + i_][j_], 0, 0, 0); }

// one K-tile: buffer b_ (literal), stages tile ktn_ into b_^1 when ST_
#define TILE(b_, ktn_, ST_) {                                                \
    bf16x8 av[4], bv[4];                                                     \
    /* ph1: ks0, M-frags 0-3 (reads A ks0 + B ks0) */                        \
    LDA4(b_, 0, 0); LDB4(b_, 0);                                             \
    if (ST_) STA(b_ ^ 1, ktn_, 0);                                           \
    SBAR(); SCHED_FENCE();                                                   \
    PRIO1(); MFMA16(0); PRIO0();                                             \
    SBAR();                                                                  \
    /* ph2: ks0, M-frags 4-7 (B regs reused) */                              \
    LDA4(b_, 0, 4);                                                          \
    if (ST_) STB(b_ ^ 1, ktn_, 0);                                           \
    SBAR(); SCHED_FENCE();                                                   \
    PRIO1(); MFMA16(4); PRIO0();                                             \
    if (ST_) { VMCNT(4); } else { VMCNT(0); }                                \
    SBAR();                                                                  \
    /* ph3: ks1, M-frags 0-3 */                                              \
    LDA4(b_, 1, 0); LDB4(b_, 1);                                             \
    if (ST_) STA(b_ ^ 1, ktn_, 1);                                           \
    SBAR(); SCHED_FENCE();                                                   \
    PRIO1(); MFMA16(0); PRIO0();                                             \
    SBAR();                                                                  \
    /* ph4: ks1, M-frags 4-7 */                                              \
    LDA4(b_, 1, 4);                                                          \
    if (ST_) STB(b_ ^ 1, ktn_, 1);                                           \
    SBAR(); SCHED_FENCE();                                                   \
    PRIO1(); MFMA16(4); PRIO0();                                             \
    if (ST_) { VMCNT(4); SBAR(); }                                           \
  }

  // prologue: stage tile0 (Aks0, Bks0, Aks1, Bks1) into buf0; wait first kslice pair
  STA(0, 0, 0); STB(0, 0, 0); STA(0, 0, 1); STB(0, 0, 1);
  VMCNT(4);
  SBAR();

#pragma unroll 1
  for (int kt = 0; kt < 14; kt += 2) {
    TILE(0, kt + 1, 1);
    TILE(1, kt + 2, 1);
  }
  TILE(0, 15, 1);   // tile 14, stages tile 15 -> buf1
  TILE(1, 0, 0);    // tile 15, no staging

  // epilogue: adjacent C-cols are (g,u) pairs for f = col>>1 (wgu interleave)
  float D = scal[0];
#pragma unroll
  for (int fr = 0; fr < 8; fr++)
#pragma unroll
    for (int fc = 0; fc < 4; fc++) {
      int row0 = (tm << 8) + (wm << 7) + (fr << 4) + ((lane >> 4) << 2);
      int col = (tn << 8) + (wn << 6) + (fc << 4) + (lane & 15);
      int f = col >> 1;
#pragma unroll
      for (int j = 0; j < 4; j++) {
        float v = acc[fr][fc][j];
        float w = __shfl_xor(v, 1);
        float g = D * ((lane & 1) ? w : v);
        float u = D * ((lane & 1) ? v : w);
        float h = (g / (1.f + __expf(-g))) * u;
        if (!(lane & 1)) hbuf[(size_t)(row0 + j) * F_SZ + f] = f2bf(h);
      }
    }
}

// ---------------- GEMM 2 (split-K, R8-verified): pbuf[kz] = h slice @ w1t slice ----------------
// tile 128x128, BK=64 single-buffered 2-barrier, swizzled LDS, XCD-bijective over 512 blocks.
__global__ __launch_bounds__(256, 2) void k_gemm_out(
    const u16* __restrict__ hbuf,  // [2048][F]
    const u16* __restrict__ w1t,   // [H=1024][F=4096] (w1^T)
    u16* __restrict__ pbuf) {      // [NSPLIT][2048][1024] bf16 partials
  __shared__ __align__(16) u16 sA[128 * 64];   // 16KB
  __shared__ __align__(16) u16 sB[128 * 64];   // 16KB

  int t = threadIdx.x;
  int lane = t & 63, wid = t >> 6;
  int wm = wid >> 1, wn = wid & 1;

  int orig = blockIdx.x + gridDim.x * (blockIdx.y + gridDim.y * blockIdx.z);
  int nwg = gridDim.x * gridDim.y * gridDim.z;   // 512
  int wg = (orig & 7) * (nwg >> 3) + (orig >> 3);
  int tm = wg & 15;
  int tn = (wg >> 4) & 7;
  int kz = wg >> 7;

  int srow = t >> 3;
  int scol = (((t & 7) ^ (srow & 7)) << 3);
  const u16* aSrc = hbuf + ((size_t)(tm << 7) + srow) * F_SZ + kz * 1024 + scol;
  const u16* bSrc = w1t + ((size_t)(tn << 7) + srow) * F_SZ + kz * 1024 + scol;
  char* aDst = (char*)sA + t * 16;
  char* bDst = (char*)sB + t * 16;

  f32x4 acc[4][4];
#pragma unroll
  for (int i = 0; i < 4; i++)
#pragma unroll
    for (int j = 0; j < 4; j++)
#pragma unroll
      for (int k = 0; k < 4; k++) acc[i][j][k] = 0.f;

  int arow = (wm << 6) + (lane & 15);
  int brow = (wn << 6) + (lane & 15);
  int sl0 = (lane >> 4) ^ (lane & 7);
  int sl1 = ((lane >> 4) | 4) ^ (lane & 7);
  const int aO0 = arow * 128 + sl0 * 16, aO1 = arow * 128 + sl1 * 16;
  const int bO0 = brow * 128 + sl0 * 16, bO1 = brow * 128 + sl1 * 16;

#pragma unroll 1
  for (int k0 = 0; k0 < 1024; k0 += 64) {
#pragma unroll
    for (int r = 0; r < 4; r++) {
      gload_lds16(aSrc + (size_t)r * 32 * F_SZ, aDst + r * 4096);
      gload_lds16(bSrc + (size_t)r * 32 * F_SZ, bDst + r * 4096);
    }
    aSrc += 64; bSrc += 64;
    __syncthreads();

    {
      bf16x8 av[4], bv[4];
#pragma unroll
      for (int fr = 0; fr < 4; fr++) av[fr] = *(const bf16x8*)((const char*)sA + aO0 + fr * 2048);
#pragma unroll
      for (int fc = 0; fc < 4; fc++) bv[fc] = *(const bf16x8*)((const char*)sB + bO0 + fc * 2048);
#pragma unroll
      for (int fr = 0; fr < 4; fr++)
#pragma unroll
        for (int fc = 0; fc < 4; fc++)
          acc[fr][fc] = __builtin_amdgcn_mfma_f32_16x16x32_bf16(av[fr], bv[fc], acc[fr][fc], 0, 0, 0);
    }
    {
      bf16x8 av[4], bv[4];
#pragma unroll
      for (int fr = 0; fr < 4; fr++) av[fr] = *(const bf16x8*)((const char*)sA + aO1 + fr * 2048);
#pragma unroll
      for (int fc = 0; fc < 4; fc++) bv[fc] = *(const bf16x8*)((const char*)sB + bO1 + fc * 2048);
#pragma unroll
      for (int fr = 0; fr < 4; fr++)
#pragma unroll
        for (int fc = 0; fc < 4; fc++)
          acc[fr][fc] = __builtin_amdgcn_mfma_f32_16x16x32_bf16(av[fr], bv[fc], acc[fr][fc], 0, 0, 0);
    }
    __syncthreads();
  }

#pragma unroll
  for (int fr = 0; fr < 4; fr++)
#pragma unroll
    for (int fc = 0; fc < 4; fc++) {
      int row0 = (tm << 7) + (wm << 6) + (fr << 4) + ((lane >> 4) << 2);
      int col = (tn << 7) + (wn << 6) + (fc << 4) + (lane & 15);
#pragma unroll
      for (int j = 0; j < 4; j++)
        pbuf[((size_t)kz * MCH + row0 + j) * 1024 + col] = f2bf(acc[fr][fc][j]);
    }
}

// ---------------- epilogue: sum split-K partials, scale by D, write out, error reduce ----------------
__global__ __launch_bounds__(256) void k_epilogue(
    const u16* __restrict__ pbuf, const float* __restrict__ x,
    float* __restrict__ out, const float* __restrict__ scal,
    float* __restrict__ partials, int chunk) {
  __shared__ float red[256];
  int t = threadIdx.x;
  size_t base = ((size_t)blockIdx.x * 256 + t) * 8;   // elem index in [2048][1024]
  int row = (int)(base >> 10);
  int col = (int)(base & 1023);
  float D = scal[0];

  float s[8] = {0.f, 0.f, 0.f, 0.f, 0.f, 0.f, 0.f, 0.f};
#pragma unroll
  for (int kz = 0; kz < NSPLIT; kz++) {
    union { bf16x8 v; u16 u[8]; } p;
    p.v = *(const bf16x8*)(pbuf + (size_t)kz * MCH * 1024 + base);
#pragma unroll
    for (int j = 0; j < 8; j++) s[j] += bf2f(p.u[j]);
  }

  int bb = row >> 9, pos = row & 511;
  size_t off = ((size_t)bb * S_SZ + (size_t)chunk * CHUNK_SZ + pos) * H_SZ + col;
  float4 x0 = *(const float4*)(x + off);
  float4 x1 = *(const float4*)(x + off + 4);
  float xv[8] = {x0.x, x0.y, x0.z, x0.w, x1.x, x1.y, x1.z, x1.w};
  float ov[8];
  float psum = 0.f;
#pragma unroll
  for (int j = 0; j < 8; j++) {
    ov[j] = D * s[j];
    float e = ov[j] - xv[j];
    psum += e * e;
  }
  *(float4*)(out + off) = make_float4(ov[0], ov[1], ov[2], ov[3]);
  *(float4*)(out + off + 4) = make_float4(ov[4], ov[5], ov[6], ov[7]);

  red[t] = psum;
  __syncthreads();
  for (int s2 = 128; s2 > 0; s2 >>= 1) {
    if (t < s2) red[t] += red[t + s2];
    __syncthreads();
  }
  if (t == 0) partials[blockIdx.x] = red[0];
}

// ---------------- scalar chain update ----------------
__global__ __launch_bounds__(256) void k_update(float* scal, const float* __restrict__ partials,
                                                float* lossout, int chunk) {
  __shared__ float red[256];
  int t = threadIdx.x;
  float s = 0.f;
  for (int i = t; i < 1024; i += 256) s += partials[i];
  red[t] = s;
  __syncthreads();
  for (int s2 = 128; s2 > 0; s2 >>= 1) {
    if (t < s2) red[t] += red[t + s2];
    __syncthreads();
  }
  if (t == 0) {
    float loss = red[0] / (float)((size_t)MCH * H_SZ);
    float total = scal[1] + loss;
    scal[1] = total;
    scal[0] = scal[0] * (1.f - LRATE * loss);
    if (chunk == NCHUNK - 1) lossout[0] = total / (float)NCHUNK;
  }
}

// ---------------- launch ----------------
extern "C" void kernel_launch(void* const* d_in, const int* in_sizes, int n_in,
                              void* d_out, int out_size, void* d_ws, size_t ws_size,
                              hipStream_t stream) {
  const float* x = (const float*)d_in[0];
  const float* w0 = (const float*)d_in[1];
  const float* w1 = (const float*)d_in[2];
  const float* w2 = (const float*)d_in[3];
  float* out = (float*)d_out;

  char* ws = (char*)d_ws;
  float* scal = (float*)ws;                    // [0]=D, [1]=total_loss
  float* partials = (float*)(ws + 1024);       // 1024 floats
  u16* xb = (u16*)(ws + 8192);                           // 16.78M elems (32MB)
  u16* wgu = xb + (size_t)B_SZ * S_SZ * H_SZ;            // 8192x1024 interleaved (16MB)
  u16* w1t = wgu + (size_t)8192 * 1024;                  // [H][F] (8MB)
  u16* hbuf = w1t + (size_t)F_SZ * H_SZ;                 // 2048x4096 (16MB)
  u16* pbuf = hbuf + (size_t)MCH * F_SZ;                 // NSPLIT x 2048x1024 (16MB)

  k_init<<<1, 256, 0, stream>>>(scal);
  k_cvt_x<<<(B_SZ * S_SZ * H_SZ) / (256 * 8), 256, 0, stream>>>(x, xb);
  // wgu rows 2f <- w0^T, rows 2f+1 <- w2^T ; w1t plain transpose
  k_transpose_cvt<<<dim3(F_SZ / 32, H_SZ / 32), 256, 0, stream>>>(w0, wgu, H_SZ, F_SZ, 2, 0);
  k_transpose_cvt<<<dim3(F_SZ / 32, H_SZ / 32), 256, 0, stream>>>(w2, wgu, H_SZ, F_SZ, 2, 1);
  k_transpose_cvt<<<dim3(H_SZ / 32, F_SZ / 32), 256, 0, stream>>>(w1, w1t, F_SZ, H_SZ, 1, 0);

  float* lossout = out + (size_t)B_SZ * S_SZ * H_SZ;
  for (int c = 0; c < NCHUNK; c++) {
    k_gemm_gu8<<<dim3(256), 512, 0, stream>>>(xb, wgu, hbuf, scal, c);
    k_gemm_out<<<dim3(16, 8, NSPLIT), 256, 0, stream>>>(hbuf, w1t, pbuf);
    k_epilogue<<<1024, 256, 0, stream>>>(pbuf, x, out, scal, partials, c);
    k_update<<<1, 256, 0, stream>>>(scal, partials, lossout, c);
  }
}

// Round 10
// 547.848 us; speedup vs baseline: 1.1906x; 1.1906x over previous
//
#include <hip/hip_runtime.h>

typedef float f32x4 __attribute__((ext_vector_type(4)));
typedef short bf16x8 __attribute__((ext_vector_type(8)));
typedef unsigned short u16;

#define B_SZ 4
#define S_SZ 4096
#define H_SZ 1024
#define F_SZ 4096
#define CHUNK_SZ 512
#define NCHUNK 8
#define MCH 2048            // rows per chunk (B*CHUNK)
#define LRATE 0.001f
#define NSPLIT 4            // split-K factor for GEMM2
#define NELEM_F 2097152.0f  // MCH * H_SZ

__device__ __forceinline__ u16 f2bf(float f) {
  unsigned u = __float_as_uint(f);
  u += 0x7FFFu + ((u >> 16) & 1u);   // round-to-nearest-even
  return (u16)(u >> 16);
}
__device__ __forceinline__ float bf2f(u16 u) {
  return __uint_as_float(((unsigned)u) << 16);
}

__device__ __forceinline__ void gload_lds16(const void* g, void* l) {
  __builtin_amdgcn_global_load_lds(
      (const __attribute__((address_space(1))) unsigned int*)g,
      (__attribute__((address_space(3))) unsigned int*)l, 16, 0, 0);
}

// ---------------- converts ----------------

__global__ __launch_bounds__(256) void k_cvt_x(const float* __restrict__ x,
                                               u16* __restrict__ xb) {
  size_t i = ((size_t)blockIdx.x * 256 + threadIdx.x) * 8;
  float4 v0 = *(const float4*)(x + i);
  float4 v1 = *(const float4*)(x + i + 4);
  union { u16 u[8]; bf16x8 v; } o;
  o.u[0] = f2bf(v0.x); o.u[1] = f2bf(v0.y); o.u[2] = f2bf(v0.z); o.u[3] = f2bf(v0.w);
  o.u[4] = f2bf(v1.x); o.u[5] = f2bf(v1.y); o.u[6] = f2bf(v1.z); o.u[7] = f2bf(v1.w);
  *(bf16x8*)(xb + i) = o.v;
}

// W [R][C] fp32  ->  Wt [C][R] bf16
__global__ __launch_bounds__(256) void k_transpose_cvt(const float* __restrict__ W,
                                                       u16* __restrict__ Wt,
                                                       int R, int C) {
  __shared__ float tile[32][33];
  int tx = threadIdx.x & 31, ty = threadIdx.x >> 5;
  int r0 = blockIdx.y << 5, c0 = blockIdx.x << 5;
#pragma unroll
  for (int i = 0; i < 4; i++)
    tile[ty + i * 8][tx] = W[(size_t)(r0 + ty + i * 8) * C + c0 + tx];
  __syncthreads();
#pragma unroll
  for (int i = 0; i < 4; i++)
    Wt[(size_t)(c0 + ty + i * 8) * R + r0 + tx] = f2bf(tile[tx][ty + i * 8]);
}

// ---------------- GEMM 1 (R8-verified): G = Xc@W0, U = Xc@W2, fused SwiGLU -> h ----------------
// tile 128(M) x 128(N) DUAL-OUTPUT, BK=64, single-buffered 2-barrier loop,
// XOR-swizzled LDS (pre-swizzled source), XCD-bijective block swizzle.
// D(chunk) recomputed in-kernel from partials (replaces scal chain).
__global__ __launch_bounds__(256, 2) void k_gemm_gu(
    const u16* __restrict__ xb,   // [B][S][H] bf16
    const u16* __restrict__ w0t,  // [F][H] bf16 (w0^T)
    const u16* __restrict__ w2t,  // [F][H]
    u16* __restrict__ hbuf,       // [2048][F] bf16
    const float* __restrict__ partials,  // [NCHUNK][1024]
    int chunk) {
  __shared__ __align__(16) u16 sA[128 * 64];    // 16KB
  __shared__ __align__(16) u16 sB0[128 * 64];   // 16KB
  __shared__ __align__(16) u16 sB2[128 * 64];   // 16KB
  __shared__ float lossL[8];

  int t = threadIdx.x;
  int lane = t & 63, wid = t >> 6;
  int wm = wid >> 1, wn = wid & 1;

  // XCD-bijective swizzle: 512 wgs / 8 XCDs -> contiguous 64-wg chunk per XCD
  int orig = blockIdx.x + (gridDim.x * blockIdx.y);
  int nwg = gridDim.x * gridDim.y;      // 512
  int wg = (orig & 7) * (nwg >> 3) + (orig >> 3);
  int tm = wg & 15, tn = wg >> 4;       // tm 0..15, tn 0..31

  int gm0 = tm << 7;               // chunk-local row 0 of tile
  int bb = gm0 >> 9;               // batch (tile never crosses batch)
  int pos0 = gm0 & 511;
  const u16* Abase = xb + ((size_t)bb * S_SZ + (size_t)chunk * CHUNK_SZ + pos0) * H_SZ;

  // staging (row = 128B = 8 slots of 16B): thread t -> row t>>3 (+32 per sweep), slot t&7.
  // source col = (slot ^ (row&7))*8 so LDS[row][slot] holds global col (slot^(row&7)).
  int srow = t >> 3;
  int scol = (((t & 7) ^ (srow & 7)) << 3);   // elements
  const u16* aSrc  = Abase + (size_t)srow * H_SZ + scol;
  const u16* b0Src = w0t + ((size_t)(tn << 7) + srow) * H_SZ + scol;
  const u16* b2Src = w2t + ((size_t)(tn << 7) + srow) * H_SZ + scol;
  char* aDst  = (char*)sA  + t * 16;
  char* b0Dst = (char*)sB0 + t * 16;
  char* b2Dst = (char*)sB2 + t * 16;

  f32x4 acc0[4][4], acc2[4][4];
#pragma unroll
  for (int i = 0; i < 4; i++)
#pragma unroll
    for (int j = 0; j < 4; j++)
#pragma unroll
      for (int k = 0; k < 4; k++) { acc0[i][j][k] = 0.f; acc2[i][j][k] = 0.f; }

  // fragment read offsets (swizzled): row&7 == lane&7 for all fr/fc
  int arow = (wm << 6) + (lane & 15);
  int brow = (wn << 6) + (lane & 15);
  int sl0 = (lane >> 4) ^ (lane & 7);
  int sl1 = ((lane >> 4) | 4) ^ (lane & 7);
  const int aO0 = arow * 128 + sl0 * 16, aO1 = arow * 128 + sl1 * 16;
  const int bO0 = brow * 128 + sl0 * 16, bO1 = brow * 128 + sl1 * 16;

#pragma unroll 1
  for (int k0 = 0; k0 < H_SZ; k0 += 64) {
#pragma unroll
    for (int r = 0; r < 4; r++) {
      gload_lds16(aSrc  + (size_t)r * 32 * H_SZ, aDst  + r * 4096);
      gload_lds16(b0Src + (size_t)r * 32 * H_SZ, b0Dst + r * 4096);
      gload_lds16(b2Src + (size_t)r * 32 * H_SZ, b2Dst + r * 4096);
    }
    aSrc += 64; b0Src += 64; b2Src += 64;
    __syncthreads();

    {
      bf16x8 av[4], b0v[4], b2v[4];
#pragma unroll
      for (int fr = 0; fr < 4; fr++) av[fr] = *(const bf16x8*)((const char*)sA + aO0 + fr * 2048);
#pragma unroll
      for (int fc = 0; fc < 4; fc++) {
        b0v[fc] = *(const bf16x8*)((const char*)sB0 + bO0 + fc * 2048);
        b2v[fc] = *(const bf16x8*)((const char*)sB2 + bO0 + fc * 2048);
      }
#pragma unroll
      for (int fr = 0; fr < 4; fr++)
#pragma unroll
        for (int fc = 0; fc < 4; fc++) {
          acc0[fr][fc] = __builtin_amdgcn_mfma_f32_16x16x32_bf16(av[fr], b0v[fc], acc0[fr][fc], 0, 0, 0);
          acc2[fr][fc] = __builtin_amdgcn_mfma_f32_16x16x32_bf16(av[fr], b2v[fc], acc2[fr][fc], 0, 0, 0);
        }
    }
    {
      bf16x8 av[4], b0v[4], b2v[4];
#pragma unroll
      for (int fr = 0; fr < 4; fr++) av[fr] = *(const bf16x8*)((const char*)sA + aO1 + fr * 2048);
#pragma unroll
      for (int fc = 0; fc < 4; fc++) {
        b0v[fc] = *(const bf16x8*)((const char*)sB0 + bO1 + fc * 2048);
        b2v[fc] = *(const bf16x8*)((const char*)sB2 + bO1 + fc * 2048);
      }
#pragma unroll
      for (int fr = 0; fr < 4; fr++)
#pragma unroll
        for (int fc = 0; fc < 4; fc++) {
          acc0[fr][fc] = __builtin_amdgcn_mfma_f32_16x16x32_bf16(av[fr], b0v[fc], acc0[fr][fc], 0, 0, 0);
          acc2[fr][fc] = __builtin_amdgcn_mfma_f32_16x16x32_bf16(av[fr], b2v[fc], acc2[fr][fc], 0, 0, 0);
        }
    }
    __syncthreads();
  }

  // ---- compute D(chunk) from partials (wave w handles prev chunk j=w) ----
  if (wid < chunk) {
    float s = 0.f;
#pragma unroll
    for (int i = 0; i < 16; i++) s += partials[wid * 1024 + lane + i * 64];
#pragma unroll
    for (int o = 32; o > 0; o >>= 1) s += __shfl_down(s, o);
    if (lane == 0) lossL[wid] = s;
  }
  __syncthreads();
  float D = 1.f;
  for (int j = 0; j < chunk; j++) D *= (1.f - LRATE * (lossL[j] / NELEM_F));

#pragma unroll
  for (int fr = 0; fr < 4; fr++)
#pragma unroll
    for (int fc = 0; fc < 4; fc++) {
      int row0 = (tm << 7) + (wm << 6) + (fr << 4) + ((lane >> 4) << 2);
      int col = (tn << 7) + (wn << 6) + (fc << 4) + (lane & 15);
#pragma unroll
      for (int j = 0; j < 4; j++) {
        float g = D * acc0[fr][fc][j];
        float u = D * acc2[fr][fc][j];
        float sil = g / (1.f + __expf(-g));
        hbuf[(size_t)(row0 + j) * F_SZ + col] = f2bf(sil * u);
      }
    }
}

// ---------------- GEMM 2 (split-K, R8-verified): pbuf[kz] = h slice @ w1t slice ----------------
// tile 128x128, BK=64 single-buffered 2-barrier, swizzled LDS, XCD-bijective over 512 blocks.
__global__ __launch_bounds__(256, 2) void k_gemm_out(
    const u16* __restrict__ hbuf,  // [2048][F]
    const u16* __restrict__ w1t,   // [H=1024][F=4096] (w1^T)
    u16* __restrict__ pbuf) {      // [NSPLIT][2048][1024] bf16 partial products
  __shared__ __align__(16) u16 sA[128 * 64];   // 16KB
  __shared__ __align__(16) u16 sB[128 * 64];   // 16KB

  int t = threadIdx.x;
  int lane = t & 63, wid = t >> 6;
  int wm = wid >> 1, wn = wid & 1;

  int orig = blockIdx.x + gridDim.x * (blockIdx.y + gridDim.y * blockIdx.z);
  int nwg = gridDim.x * gridDim.y * gridDim.z;   // 512
  int wg = (orig & 7) * (nwg >> 3) + (orig >> 3);
  int tm = wg & 15;
  int tn = (wg >> 4) & 7;
  int kz = wg >> 7;

  int srow = t >> 3;
  int scol = (((t & 7) ^ (srow & 7)) << 3);
  const u16* aSrc = hbuf + ((size_t)(tm << 7) + srow) * F_SZ + kz * 1024 + scol;
  const u16* bSrc = w1t + ((size_t)(tn << 7) + srow) * F_SZ + kz * 1024 + scol;
  char* aDst = (char*)sA + t * 16;
  char* bDst = (char*)sB + t * 16;

  f32x4 acc[4][4];
#pragma unroll
  for (int i = 0; i < 4; i++)
#pragma unroll
    for (int j = 0; j < 4; j++)
#pragma unroll
      for (int k = 0; k < 4; k++) acc[i][j][k] = 0.f;

  int arow = (wm << 6) + (lane & 15);
  int brow = (wn << 6) + (lane & 15);
  int sl0 = (lane >> 4) ^ (lane & 7);
  int sl1 = ((lane >> 4) | 4) ^ (lane & 7);
  const int aO0 = arow * 128 + sl0 * 16, aO1 = arow * 128 + sl1 * 16;
  const int bO0 = brow * 128 + sl0 * 16, bO1 = brow * 128 + sl1 * 16;

#pragma unroll 1
  for (int k0 = 0; k0 < 1024; k0 += 64) {
#pragma unroll
    for (int r = 0; r < 4; r++) {
      gload_lds16(aSrc + (size_t)r * 32 * F_SZ, aDst + r * 4096);
      gload_lds16(bSrc + (size_t)r * 32 * F_SZ, bDst + r * 4096);
    }
    aSrc += 64; bSrc += 64;
    __syncthreads();

    {
      bf16x8 av[4], bv[4];
#pragma unroll
      for (int fr = 0; fr < 4; fr++) av[fr] = *(const bf16x8*)((const char*)sA + aO0 + fr * 2048);
#pragma unroll
      for (int fc = 0; fc < 4; fc++) bv[fc] = *(const bf16x8*)((const char*)sB + bO0 + fc * 2048);
#pragma unroll
      for (int fr = 0; fr < 4; fr++)
#pragma unroll
        for (int fc = 0; fc < 4; fc++)
          acc[fr][fc] = __builtin_amdgcn_mfma_f32_16x16x32_bf16(av[fr], bv[fc], acc[fr][fc], 0, 0, 0);
    }
    {
      bf16x8 av[4], bv[4];
#pragma unroll
      for (int fr = 0; fr < 4; fr++) av[fr] = *(const bf16x8*)((const char*)sA + aO1 + fr * 2048);
#pragma unroll
      for (int fc = 0; fc < 4; fc++) bv[fc] = *(const bf16x8*)((const char*)sB + bO1 + fc * 2048);
#pragma unroll
      for (int fr = 0; fr < 4; fr++)
#pragma unroll
        for (int fc = 0; fc < 4; fc++)
          acc[fr][fc] = __builtin_amdgcn_mfma_f32_16x16x32_bf16(av[fr], bv[fc], acc[fr][fc], 0, 0, 0);
    }
    __syncthreads();
  }

#pragma unroll
  for (int fr = 0; fr < 4; fr++)
#pragma unroll
    for (int fc = 0; fc < 4; fc++) {
      int row0 = (tm << 7) + (wm << 6) + (fr << 4) + ((lane >> 4) << 2);
      int col = (tn << 7) + (wn << 6) + (fc << 4) + (lane & 15);
#pragma unroll
      for (int j = 0; j < 4; j++)
        pbuf[((size_t)kz * MCH + row0 + j) * 1024 + col] = f2bf(acc[fr][fc][j]);
    }
}

// ---------------- epilogue: sum split-K partials, scale by D, write out, error reduce ----------------
__global__ __launch_bounds__(256) void k_epilogue(
    const u16* __restrict__ pbuf, const float* __restrict__ x,
    float* __restrict__ out,
    float* __restrict__ partials,   // [NCHUNK][1024]; reads j<chunk, writes [chunk][bid]
    int chunk) {
  __shared__ float red[256];
  __shared__ float lossL[8];
  int t = threadIdx.x;
  int lane = t & 63, wid = t >> 6;

  // ---- compute D(chunk) from partials of previous chunks (same order as gu) ----
  for (int j = wid; j < chunk; j += 4) {
    float s = 0.f;
#pragma unroll
    for (int i = 0; i < 16; i++) s += partials[j * 1024 + lane + i * 64];
#pragma unroll
    for (int o = 32; o > 0; o >>= 1) s += __shfl_down(s, o);
    if (lane == 0) lossL[j] = s;
  }
  __syncthreads();
  float D = 1.f;
  for (int j = 0; j < chunk; j++) D *= (1.f - LRATE * (lossL[j] / NELEM_F));

  size_t base = ((size_t)blockIdx.x * 256 + t) * 8;   // elem index in [2048][1024]
  int row = (int)(base >> 10);
  int col = (int)(base & 1023);

  float s[8] = {0.f, 0.f, 0.f, 0.f, 0.f, 0.f, 0.f, 0.f};
#pragma unroll
  for (int kz = 0; kz < NSPLIT; kz++) {
    union { bf16x8 v; u16 u[8]; } p;
    p.v = *(const bf16x8*)(pbuf + (size_t)kz * MCH * 1024 + base);
#pragma unroll
    for (int j = 0; j < 8; j++) s[j] += bf2f(p.u[j]);
  }

  int bb = row >> 9, pos = row & 511;
  size_t off = ((size_t)bb * S_SZ + (size_t)chunk * CHUNK_SZ + pos) * H_SZ + col;
  float4 x0 = *(const float4*)(x + off);
  float4 x1 = *(const float4*)(x + off + 4);
  float xv[8] = {x0.x, x0.y, x0.z, x0.w, x1.x, x1.y, x1.z, x1.w};
  float ov[8];
  float psum = 0.f;
#pragma unroll
  for (int j = 0; j < 8; j++) {
    ov[j] = D * s[j];
    float e = ov[j] - xv[j];
    psum += e * e;
  }
  *(float4*)(out + off) = make_float4(ov[0], ov[1], ov[2], ov[3]);
  *(float4*)(out + off + 4) = make_float4(ov[4], ov[5], ov[6], ov[7]);

  red[t] = psum;
  __syncthreads();
  for (int s2 = 128; s2 > 0; s2 >>= 1) {
    if (t < s2) red[t] += red[t + s2];
    __syncthreads();
  }
  if (t == 0) partials[chunk * 1024 + blockIdx.x] = red[0];
}

// ---------------- final loss output (single launch after all chunks) ----------------
__global__ __launch_bounds__(256) void k_update_final(const float* __restrict__ partials,
                                                      float* __restrict__ lossout) {
  __shared__ float red[256];
  int t = threadIdx.x;
  float s = 0.f;
  for (int i = t; i < NCHUNK * 1024; i += 256) s += partials[i];
  red[t] = s;
  __syncthreads();
  for (int s2 = 128; s2 > 0; s2 >>= 1) {
    if (t < s2) red[t] += red[t + s2];
    __syncthreads();
  }
  if (t == 0) lossout[0] = (red[0] / NELEM_F) / (float)NCHUNK;
}

// ---------------- launch ----------------
extern "C" void kernel_launch(void* const* d_in, const int* in_sizes, int n_in,
                              void* d_out, int out_size, void* d_ws, size_t ws_size,
                              hipStream_t stream) {
  const float* x = (const float*)d_in[0];
  const float* w0 = (const float*)d_in[1];
  const float* w1 = (const float*)d_in[2];
  const float* w2 = (const float*)d_in[3];
  float* out = (float*)d_out;

  char* ws = (char*)d_ws;
  float* partials = (float*)ws;                          // [NCHUNK][1024] floats (32KB)
  u16* xb = (u16*)(ws + 40960);                          // 16M elems (32MB)
  u16* w0t = xb + (size_t)B_SZ * S_SZ * H_SZ;            // 4M (8MB)
  u16* w2t = w0t + (size_t)H_SZ * F_SZ;                  // 4M
  u16* w1t = w2t + (size_t)H_SZ * F_SZ;                  // 4M
  u16* hbuf = w1t + (size_t)F_SZ * H_SZ;                 // 8M elems (16MB)
  u16* pbuf = hbuf + (size_t)MCH * F_SZ;                 // NSPLIT*2M elems (16MB)

  k_cvt_x<<<(B_SZ * S_SZ * H_SZ) / (256 * 8), 256, 0, stream>>>(x, xb);
  k_transpose_cvt<<<dim3(F_SZ / 32, H_SZ / 32), 256, 0, stream>>>(w0, w0t, H_SZ, F_SZ);
  k_transpose_cvt<<<dim3(H_SZ / 32, F_SZ / 32), 256, 0, stream>>>(w1, w1t, F_SZ, H_SZ);
  k_transpose_cvt<<<dim3(F_SZ / 32, H_SZ / 32), 256, 0, stream>>>(w2, w2t, H_SZ, F_SZ);

  float* lossout = out + (size_t)B_SZ * S_SZ * H_SZ;
  for (int c = 0; c < NCHUNK; c++) {
    k_gemm_gu<<<dim3(16, 32), 256, 0, stream>>>(xb, w0t, w2t, hbuf, partials, c);
    k_gemm_out<<<dim3(16, 8, NSPLIT), 256, 0, stream>>>(hbuf, w1t, pbuf);
    k_epilogue<<<1024, 256, 0, stream>>>(pbuf, x, out, partials, c);
  }
  k_update_final<<<1, 256, 0, stream>>>(partials, lossout);
}